// Round 1
// baseline (459.110 us; speedup 1.0000x reference)
//
#include <hip/hip_runtime.h>
#include <hip/hip_bf16.h>
#include <math.h>

// Problem constants
#define Ln     35
#define CINn   21
#define CINP   24        // padded CIN (multiple of 8 -> aligned b128 im2col reads)
#define Fn     128
#define Kn     9
#define Hn     64
#define GB     16        // batch rows per block
#define SEQ_STRIDE 1064  // 44 rows*24 + 8 slack (shorts); l=35 window ends at 1064
#define TILE_STRIDE 136  // 128 + 8 pad (shorts)
#define YL0    10        // first l whose MLP output is ever consumed
#define YL1    24        // last  l whose MLP output is ever consumed (plen<=15)
#define NYL    15        // YL1-YL0+1

typedef __attribute__((ext_vector_type(8))) short short8;
typedef __attribute__((ext_vector_type(4))) float f32x4;

static __device__ __forceinline__ unsigned short bf16bits(float f) {
    __hip_bfloat16 h = __float2bfloat16(f);
    return *(unsigned short*)&h;
}

// ---------------- single fused kernel: 16 batch rows / block, 512 threads ----------------
// 8 waves/block; wave w owns conv f-tile [16w,16w+16) and MLP n-tile [16w,16w+16)
// (n<64 = n-head, n>=64 = c-head).
// vs previous version: MLP (+tile write +barrier) only for l in [10,24] — the only l's
// whose y is consumed (cleaved/mask ranges with plen<=15). y partials accumulate via
// LDS atomicAdd into s_yp[15][2][16] (f32), killing the 17.9KB partial buffer and its
// 32-way-conflict finalize reads. LDS 69.6KB -> 53.4KB => 3 blocks/CU (24 waves).
__global__ __launch_bounds__(512, 4) void fused_kernel(
    const float* __restrict__ seq,    const int*   __restrict__ plen_arr,
    const float* __restrict__ conv_w, const float* __restrict__ conv_b,
    const float* __restrict__ n_w1,   const float* __restrict__ n_b1,
    const float* __restrict__ n_w2,   const float* __restrict__ n_b2,
    const float* __restrict__ c_w1,   const float* __restrict__ c_b1,
    const float* __restrict__ c_w2,   const float* __restrict__ c_b2,
    const float* __restrict__ navg_w, const float* __restrict__ navg_b,
    const float* __restrict__ cavg_w, const float* __restrict__ cavg_b,
    const float* __restrict__ out_w,  const float* __restrict__ out_b,
    float* __restrict__ out)
{
    __shared__ __align__(16) unsigned short s_seq[GB * SEQ_STRIDE];      // 34048 B
    __shared__ __align__(16) unsigned short s_tile[4][GB * TILE_STRIDE]; // 17408 B
    __shared__ __align__(16) float s_yp[NYL * 2 * GB];                   // 1920 B: [l-10][head][m]
    // overlay on s_seq (dead after the main loop):
    float* s_avg = (float*)s_seq;            // [8 waves][2][GB] = 256 floats

    const int t    = threadIdx.x;
    const int wave = t >> 6;                 // 0..7
    const int lane = t & 63;
    const int quad = lane >> 4;
    const int col  = lane & 15;
    const int b0   = blockIdx.x * GB;

    // ---- zero-init padded seq (pad rows/channels + slack must be 0) + y accumulator ----
    {
        uint4* p = (uint4*)s_seq;            // 34048/16 = 2128 uint4
        for (int i = t; i < (GB * SEQ_STRIDE) / 8; i += 512)
            p[i] = make_uint4(0u, 0u, 0u, 0u);
        if (t < NYL * 2 * GB) s_yp[t] = 0.0f;
    }

    // ---- per-lane loop-invariant weight fragments (single tile per wave) ----
    // conv A-frag (operand-swapped): A[m=f=16*wave+col][k=kk], kk = k*24+c
    // MLP  B-frag: B[k=f][n=16*wave+col]
    short8 wb[7];
    short8 w1b[4];
    float  cbias[4], b1v, w2v;
    const int head = wave >> 2;              // 0 = n-head (waves 0-3), 1 = c (waves 4-7)
    {
        const int ng = wave * 16 + col;      // conv f (A m-index) AND mlp n-index
        #pragma unroll
        for (int s = 0; s < 7; s++) {
            short8 v;
            #pragma unroll
            for (int j = 0; j < 8; j++) {
                int kk = 32 * s + quad * 8 + j;
                int k = kk / CINP, c = kk % CINP;
                float f = (k < Kn && c < CINn) ? conv_w[(k * CINn + c) * Fn + ng] : 0.0f;
                v[j] = (short)bf16bits(f);
            }
            wb[s] = v;
        }
        const int nl = ng & 63;
        #pragma unroll
        for (int s = 0; s < 4; s++) {
            short8 v;
            #pragma unroll
            for (int j = 0; j < 8; j++) {
                int k = 32 * s + quad * 8 + j;
                float f = head ? c_w1[k * Hn + nl] : n_w1[k * Hn + nl];
                v[j] = (short)bf16bits(f);
            }
            w1b[s] = v;
        }
        #pragma unroll
        for (int r = 0; r < 4; r++)
            cbias[r] = conv_b[wave * 16 + 4 * quad + r];
        b1v = head ? c_b1[nl] : n_b1[nl];
        w2v = head ? c_w2[nl] : n_w2[nl];
    }
    const int plen_lane = plen_arr[b0 + col];   // this lane's batch (=col) plen

    __syncthreads();   // zero-init done before data fill

    // ---- stage seq -> bf16 LDS, rows shifted +4 (SAME pad), c<21 only ----
    // incremental (bi,l,c) walk: step 512 = 24 rows + 8 cols (avoids div/mod per iter)
    {
        int i  = t;
        int bi = i / (Ln * CINn);
        int r  = i - bi * (Ln * CINn);
        int l  = r / CINn;
        int c  = r - l * CINn;
        for (; i < GB * Ln * CINn; i += 512) {
            s_seq[bi * SEQ_STRIDE + (4 + l) * CINP + c] =
                bf16bits(seq[(size_t)b0 * (Ln * CINn) + i]);
            c += 8;  if (c >= CINn) { c -= CINn; ++l; }
            l += 24; if (l >= Ln)   { l -= Ln;  ++bi; }
        }
    }
    __syncthreads();

    float sum_n[4] = {0.f,0.f,0.f,0.f};
    float sum_c[4] = {0.f,0.f,0.f,0.f};

    // ---- main loop: 2 l per stage, 18 stages. Conv runs for ALL l (flank sums need it);
    // MLP + tile write + barrier ONLY for l in [10,24] (8 barrier stages). 4-slot ring on
    // s_tile: stage l0 writes slots {l0&3,(l0+1)&3}; WAR separated by the next mlp barrier.
    // l=35 is a computed pad column (auto-masked from sums).
    for (int l0 = 0; l0 < 36; l0 += 2) {
        const int  l1   = l0 + 1;
        const bool mlp  = (l0 >= YL0 && l0 <= YL1);   // block-uniform
        const bool has1 = (l1 <= YL1);                // block-uniform
        // ---- conv GEMM (operand-swapped): D^T[f][batch], wave's 16-f tile ----
        short8 af0[7], af1[7];
        #pragma unroll
        for (int s = 0; s < 7; s++) {
            af0[s] = *(const short8*)&s_seq[col * SEQ_STRIDE + l0 * CINP + 32 * s + quad * 8];
            af1[s] = *(const short8*)&s_seq[col * SEQ_STRIDE + l1 * CINP + 32 * s + quad * 8];
        }
        f32x4 cacc0 = {0.f,0.f,0.f,0.f};
        f32x4 cacc1 = {0.f,0.f,0.f,0.f};
        #pragma unroll
        for (int s = 0; s < 7; s++) {
            cacc0 = __builtin_amdgcn_mfma_f32_16x16x32_bf16(wb[s], af0[s], cacc0, 0, 0, 0);
            cacc1 = __builtin_amdgcn_mfma_f32_16x16x32_bf16(wb[s], af1[s], cacc1, 0, 0, 0);
        }
        // ---- epilogue: lane holds batch=col, f = 16*wave + 4q + r ----
        float a0 = fmaxf(cacc0[0] + cbias[0], 0.0f);
        float a1 = fmaxf(cacc0[1] + cbias[1], 0.0f);
        float a2 = fmaxf(cacc0[2] + cbias[2], 0.0f);
        float a3 = fmaxf(cacc0[3] + cbias[3], 0.0f);
        float e0 = fmaxf(cacc1[0] + cbias[0], 0.0f);
        float e1 = fmaxf(cacc1[1] + cbias[1], 0.0f);
        float e2 = fmaxf(cacc1[2] + cbias[2], 0.0f);
        float e3 = fmaxf(cacc1[3] + cbias[3], 0.0f);
        if (l0 < 10) {            // wave-uniform; l1<10 iff l0<10 (l0 even)
            sum_n[0] += a0 + e0; sum_n[1] += a1 + e1;
            sum_n[2] += a2 + e2; sum_n[3] += a3 + e3;
        }
        if (l1 >= 15) {           // cm can only be nonzero for l >= 10+plen >= 15
            float cm0 = (l0 >= 10 + plen_lane && l0 < 20 + plen_lane) ? 1.0f : 0.0f;
            float cm1 = (l1 >= 10 + plen_lane && l1 < 20 + plen_lane) ? 1.0f : 0.0f;
            sum_c[0] += cm0 * a0 + cm1 * e0;
            sum_c[1] += cm0 * a1 + cm1 * e1;
            sum_c[2] += cm0 * a2 + cm1 * e2;
            sum_c[3] += cm0 * a3 + cm1 * e3;
        }
        if (mlp) {
            ushort4 pk0 = { bf16bits(a0), bf16bits(a1), bf16bits(a2), bf16bits(a3) };
            *(ushort4*)&s_tile[l0 & 3][col * TILE_STRIDE + wave * 16 + 4 * quad] = pk0;
            if (has1) {
                ushort4 pk1 = { bf16bits(e0), bf16bits(e1), bf16bits(e2), bf16bits(e3) };
                *(ushort4*)&s_tile[l1 & 3][col * TILE_STRIDE + wave * 16 + 4 * quad] = pk1;
            }
            __syncthreads();   // conv tiles written -> MLP may read; WAR fence for ring

            // ---- MLP layer1 GEMM: D[m=batch][n = wave's 16-n tile], K = 128 f ----
            short8 am0[4], am1[4];
            #pragma unroll
            for (int s = 0; s < 4; s++) {
                am0[s] = *(const short8*)&s_tile[l0 & 3][col * TILE_STRIDE + 32 * s + quad * 8];
                if (has1)
                    am1[s] = *(const short8*)&s_tile[l1 & 3][col * TILE_STRIDE + 32 * s + quad * 8];
            }
            f32x4 hacc0 = {0.f,0.f,0.f,0.f};
            f32x4 hacc1 = {0.f,0.f,0.f,0.f};
            #pragma unroll
            for (int s = 0; s < 4; s++) {
                hacc0 = __builtin_amdgcn_mfma_f32_16x16x32_bf16(am0[s], w1b[s], hacc0, 0, 0, 0);
                if (has1)
                    hacc1 = __builtin_amdgcn_mfma_f32_16x16x32_bf16(am1[s], w1b[s], hacc1, 0, 0, 0);
            }
            // ---- y partial = relu(h+b1) @ w2 over this wave's 16 n; reduce cols ----
            float p0[4], p1[4];
            #pragma unroll
            for (int r = 0; r < 4; r++) {
                p0[r] = fmaxf(hacc0[r] + b1v, 0.f) * w2v;
                if (has1) p1[r] = fmaxf(hacc1[r] + b1v, 0.f) * w2v;
            }
            #pragma unroll
            for (int r = 0; r < 4; r++) {
                p0[r] += __shfl_xor(p0[r], 1);
                p0[r] += __shfl_xor(p0[r], 2);
                p0[r] += __shfl_xor(p0[r], 4);
                p0[r] += __shfl_xor(p0[r], 8);
                if (has1) {
                    p1[r] += __shfl_xor(p1[r], 1);
                    p1[r] += __shfl_xor(p1[r], 2);
                    p1[r] += __shfl_xor(p1[r], 4);
                    p1[r] += __shfl_xor(p1[r], 8);
                }
            }
            if (col == 0) {       // 4 lanes/wave; 4-way cross-wave contention per address
                const int base0 = (l0 - YL0) * 32 + head * 16 + quad * 4;
                atomicAdd(&s_yp[base0 + 0], p0[0]);
                atomicAdd(&s_yp[base0 + 1], p0[1]);
                atomicAdd(&s_yp[base0 + 2], p0[2]);
                atomicAdd(&s_yp[base0 + 3], p0[3]);
                if (has1) {
                    const int base1 = (l1 - YL0) * 32 + head * 16 + quad * 4;
                    atomicAdd(&s_yp[base1 + 0], p1[0]);
                    atomicAdd(&s_yp[base1 + 1], p1[1]);
                    atomicAdd(&s_yp[base1 + 2], p1[2]);
                    atomicAdd(&s_yp[base1 + 3], p1[3]);
                }
            }
        }
    }
    __syncthreads();   // all s_seq reads + s_yp atomics done -> overlay safe

    // ---- flank-average partials: apply navg_w/cavg_w post-loop ----
    {
        float an = 0.f, ac = 0.f;
        #pragma unroll
        for (int r = 0; r < 4; r++) {
            int fidx = wave * 16 + 4 * quad + r;
            an += sum_n[r] * navg_w[fidx];
            ac += sum_c[r] * cavg_w[fidx];
        }
        an += __shfl_xor(an, 16); an += __shfl_xor(an, 32);   // sum over quads
        ac += __shfl_xor(ac, 16); ac += __shfl_xor(ac, 32);
        if (quad == 0) {                     // lane < 16: one per batch
            s_avg[wave * 2 * GB + 0 * GB + col] = an;
            s_avg[wave * 2 * GB + 1 * GB + col] = ac;
        }
    }
    // ---- y finalize in place: y = tanh(sum + b2), 480 values, conflict-free ----
    if (t < NYL * 2 * GB) {
        const int hd = (t >> 4) & 1;
        s_yp[t] = tanhf(s_yp[t] + (hd ? c_b2[0] : n_b2[0]));
    }
    __syncthreads();

    // ---- final combine: one thread per batch row ----
    if (t < GB) {
        const int m = t;
        const int plen = plen_arr[b0 + m];
        // s_yp[(l-10)*32 + head*16 + m]; lane m stays in its own bank
        float cleaved_n = s_yp[m];                              // l = 10, n-head
        float mn = 0.f;   // reference maxes (y+1)*mask over ALL l; unmasked give 0
        for (int l = 11; l < 10 + plen; l++)
            mn = fmaxf(mn, s_yp[(l - YL0) * 32 + m] + 1.f);
        float maxpool_n = -(mn - 1.f);
        float cleaved_c = s_yp[(plen - 1) * 32 + 16 + m];       // l = 10+plen-1, c-head
        float mc = 0.f;
        for (int l = 10; l < 10 + plen - 1; l++)
            mc = fmaxf(mc, s_yp[(l - YL0) * 32 + 16 + m] + 1.f);
        float maxpool_c = -(mc - 1.f);
        float sn = 0.f, sc = 0.f;
        #pragma unroll
        for (int w = 0; w < 8; w++) {
            sn += s_avg[w * 2 * GB + 0 * GB + m];
            sc += s_avg[w * 2 * GB + 1 * GB + m];
        }
        float avg_n = tanhf(sn * 0.1f + navg_b[0]);
        float avg_c = tanhf(sc * 0.1f + cavg_b[0]);
        float comb = cleaved_n * out_w[0] + maxpool_n * out_w[1] + avg_n * out_w[2]
                   + cleaved_c * out_w[3] + maxpool_c * out_w[4] + avg_c * out_w[5]
                   + out_b[0];
        out[b0 + m] = 1.f / (1.f + expf(-comb));
    }
}

extern "C" void kernel_launch(void* const* d_in, const int* in_sizes, int n_in,
                              void* d_out, int out_size, void* d_ws, size_t ws_size,
                              hipStream_t stream) {
    const int B = in_sizes[1];
    fused_kernel<<<B / GB, 512, 0, stream>>>(
        (const float*)d_in[0],  (const int*)d_in[1],
        (const float*)d_in[2],  (const float*)d_in[3],
        (const float*)d_in[4],  (const float*)d_in[5],
        (const float*)d_in[6],  (const float*)d_in[7],
        (const float*)d_in[8],  (const float*)d_in[9],
        (const float*)d_in[10], (const float*)d_in[11],
        (const float*)d_in[12], (const float*)d_in[13],
        (const float*)d_in[14], (const float*)d_in[15],
        (const float*)d_in[16], (const float*)d_in[17],
        (float*)d_out);
}

// Round 2
// 423.971 us; speedup vs baseline: 1.0829x; 1.0829x over previous
//
#include <hip/hip_runtime.h>
#include <hip/hip_bf16.h>
#include <math.h>

// Problem constants
#define Ln     35
#define CINn   21
#define CINP   24        // padded CIN (multiple of 8 -> aligned b128 im2col reads)
#define Fn     128
#define Kn     9
#define Hn     64
#define GB     16        // batch rows per block
#define SEQ_STRIDE 1064  // 44 rows*24 + 8 slack (shorts); l=35 window ends at 1064
#define TILE_STRIDE 136  // 128 + 8 pad (shorts)
#define YL0    10        // first l whose MLP output is ever consumed
#define NYL    15        // l in [10,24] consumed (plen<=15)

typedef __attribute__((ext_vector_type(8))) short short8;
typedef __attribute__((ext_vector_type(4))) float f32x4;

static __device__ __forceinline__ unsigned short bf16bits(float f) {
    __hip_bfloat16 h = __float2bfloat16(f);
    return *(unsigned short*)&h;
}

// conv GEMM pair for (L0, L0+1): declares A0..A3 (l=L0), E0..E3 (l=L0+1) relu'd outputs.
// Straight-line, no branches; wb/cbias/col/quad/s_seq captured from scope.
#define CONV_PAIR(L0, A0,A1,A2,A3, E0,E1,E2,E3)                                            \
    float A0,A1,A2,A3,E0,E1,E2,E3;                                                         \
    {                                                                                      \
        short8 af0[7], af1[7];                                                             \
        _Pragma("unroll")                                                                  \
        for (int s = 0; s < 7; s++) {                                                      \
            af0[s] = *(const short8*)&s_seq[col*SEQ_STRIDE + (L0)*CINP   + 32*s + quad*8]; \
            af1[s] = *(const short8*)&s_seq[col*SEQ_STRIDE + ((L0)+1)*CINP + 32*s + quad*8]; \
        }                                                                                  \
        f32x4 c0 = {0.f,0.f,0.f,0.f}, c1 = {0.f,0.f,0.f,0.f};                              \
        _Pragma("unroll")                                                                  \
        for (int s = 0; s < 7; s++) {                                                      \
            c0 = __builtin_amdgcn_mfma_f32_16x16x32_bf16(wb[s], af0[s], c0, 0, 0, 0);      \
            c1 = __builtin_amdgcn_mfma_f32_16x16x32_bf16(wb[s], af1[s], c1, 0, 0, 0);      \
        }                                                                                  \
        A0 = fmaxf(c0[0] + cbias[0], 0.f); A1 = fmaxf(c0[1] + cbias[1], 0.f);              \
        A2 = fmaxf(c0[2] + cbias[2], 0.f); A3 = fmaxf(c0[3] + cbias[3], 0.f);              \
        E0 = fmaxf(c1[0] + cbias[0], 0.f); E1 = fmaxf(c1[1] + cbias[1], 0.f);              \
        E2 = fmaxf(c1[2] + cbias[2], 0.f); E3 = fmaxf(c1[3] + cbias[3], 0.f);              \
    }

// MLP for one l (slot = l&3): layer1 GEMM + relu*w2 + 16-col reduce + s_yp atomic add.
#define MLP_ONE(L)                                                                         \
    {                                                                                      \
        short8 am[4];                                                                      \
        _Pragma("unroll")                                                                  \
        for (int s = 0; s < 4; s++)                                                        \
            am[s] = *(const short8*)&s_tile[(L) & 3][col*TILE_STRIDE + 32*s + quad*8];     \
        f32x4 h = {0.f,0.f,0.f,0.f};                                                       \
        _Pragma("unroll")                                                                  \
        for (int s = 0; s < 4; s++)                                                        \
            h = __builtin_amdgcn_mfma_f32_16x16x32_bf16(am[s], w1b[s], h, 0, 0, 0);        \
        float p[4];                                                                        \
        _Pragma("unroll")                                                                  \
        for (int r = 0; r < 4; r++)                                                        \
            p[r] = fmaxf(h[r] + b1v, 0.f) * w2v;                                           \
        _Pragma("unroll")                                                                  \
        for (int r = 0; r < 4; r++) {                                                      \
            p[r] += __shfl_xor(p[r], 1);                                                   \
            p[r] += __shfl_xor(p[r], 2);                                                   \
            p[r] += __shfl_xor(p[r], 4);                                                   \
            p[r] += __shfl_xor(p[r], 8);                                                   \
        }                                                                                  \
        if (col == 0) {                                                                    \
            const int base = ((L) - YL0) * 32 + head * 16 + quad * 4;                      \
            atomicAdd(&s_yp[base + 0], p[0]);                                              \
            atomicAdd(&s_yp[base + 1], p[1]);                                              \
            atomicAdd(&s_yp[base + 2], p[2]);                                              \
            atomicAdd(&s_yp[base + 3], p[3]);                                              \
        }                                                                                  \
    }

// ---------------- single fused kernel: 16 batch rows / block, 512 threads ----------------
// 8 waves/block; wave w owns conv f-tile [16w,16w+16) and MLP n-tile [16w,16w+16)
// (n<64 = n-head, n>=64 = c-head).
// Structure: four straight-line regions (NO runtime branches in bodies -> no spill):
//   pre  l=0..9   : conv + sum_n only, no barriers
//   mid  l0=10..22: conv + sum_c + tile write + barrier + MLP both l  (round-0 stage shape)
//   peel l0=24    : conv(24,25) + sum_c + tile write(24) + barrier + MLP(24)
//   post l=26..35 : conv + sum_c only, no barriers (l=35 = computed pad, cm auto-false)
// y partials accumulate via LDS atomicAdd into s_yp[15][2][16] f32 (1.9 KB).
__global__ __launch_bounds__(512, 4) void fused_kernel(
    const float* __restrict__ seq,    const int*   __restrict__ plen_arr,
    const float* __restrict__ conv_w, const float* __restrict__ conv_b,
    const float* __restrict__ n_w1,   const float* __restrict__ n_b1,
    const float* __restrict__ n_w2,   const float* __restrict__ n_b2,
    const float* __restrict__ c_w1,   const float* __restrict__ c_b1,
    const float* __restrict__ c_w2,   const float* __restrict__ c_b2,
    const float* __restrict__ navg_w, const float* __restrict__ navg_b,
    const float* __restrict__ cavg_w, const float* __restrict__ cavg_b,
    const float* __restrict__ out_w,  const float* __restrict__ out_b,
    float* __restrict__ out)
{
    __shared__ __align__(16) unsigned short s_seq[GB * SEQ_STRIDE];      // 34048 B
    __shared__ __align__(16) unsigned short s_tile[4][GB * TILE_STRIDE]; // 17408 B
    __shared__ __align__(16) float s_yp[NYL * 2 * GB];                   // 1920 B: [l-10][head][m]
    // overlay on s_seq (dead after the main loops):
    float* s_avg = (float*)s_seq;            // [8 waves][2][GB] = 256 floats

    const int t    = threadIdx.x;
    const int wave = t >> 6;                 // 0..7
    const int lane = t & 63;
    const int quad = lane >> 4;
    const int col  = lane & 15;
    const int b0   = blockIdx.x * GB;

    // ---- zero-init padded seq (pad rows/channels + slack must be 0) + y accumulator ----
    {
        uint4* p = (uint4*)s_seq;            // 34048/16 = 2128 uint4
        for (int i = t; i < (GB * SEQ_STRIDE) / 8; i += 512)
            p[i] = make_uint4(0u, 0u, 0u, 0u);
        if (t < NYL * 2 * GB) s_yp[t] = 0.0f;
    }

    // ---- per-lane loop-invariant weight fragments (single tile per wave) ----
    // conv A-frag (operand-swapped): A[m=f=16*wave+col][k=kk], kk = k*24+c
    // MLP  B-frag: B[k=f][n=16*wave+col]
    short8 wb[7];
    short8 w1b[4];
    float  cbias[4], b1v, w2v;
    const int head = wave >> 2;              // 0 = n-head (waves 0-3), 1 = c (waves 4-7)
    {
        const int ng = wave * 16 + col;      // conv f (A m-index) AND mlp n-index
        #pragma unroll
        for (int s = 0; s < 7; s++) {
            short8 v;
            #pragma unroll
            for (int j = 0; j < 8; j++) {
                int kk = 32 * s + quad * 8 + j;
                int k = kk / CINP, c = kk % CINP;
                float f = (k < Kn && c < CINn) ? conv_w[(k * CINn + c) * Fn + ng] : 0.0f;
                v[j] = (short)bf16bits(f);
            }
            wb[s] = v;
        }
        const int nl = ng & 63;
        #pragma unroll
        for (int s = 0; s < 4; s++) {
            short8 v;
            #pragma unroll
            for (int j = 0; j < 8; j++) {
                int k = 32 * s + quad * 8 + j;
                float f = head ? c_w1[k * Hn + nl] : n_w1[k * Hn + nl];
                v[j] = (short)bf16bits(f);
            }
            w1b[s] = v;
        }
        #pragma unroll
        for (int r = 0; r < 4; r++)
            cbias[r] = conv_b[wave * 16 + 4 * quad + r];
        b1v = head ? c_b1[nl] : n_b1[nl];
        w2v = head ? c_w2[nl] : n_w2[nl];
    }
    const int plen_lane = plen_arr[b0 + col];   // this lane's batch (=col) plen

    __syncthreads();   // zero-init done before data fill

    // ---- stage seq -> bf16 LDS, rows shifted +4 (SAME pad), c<21 only ----
    // incremental (bi,l,c) walk: step 512 = 24 rows + 8 cols (avoids div/mod per iter)
    {
        int i  = t;
        int bi = i / (Ln * CINn);
        int r  = i - bi * (Ln * CINn);
        int l  = r / CINn;
        int c  = r - l * CINn;
        for (; i < GB * Ln * CINn; i += 512) {
            s_seq[bi * SEQ_STRIDE + (4 + l) * CINP + c] =
                bf16bits(seq[(size_t)b0 * (Ln * CINn) + i]);
            c += 8;  if (c >= CINn) { c -= CINn; ++l; }
            l += 24; if (l >= Ln)   { l -= Ln;  ++bi; }
        }
    }
    __syncthreads();

    float sum_n[4] = {0.f,0.f,0.f,0.f};
    float sum_c[4] = {0.f,0.f,0.f,0.f};

    // ======== PRE: l = 0..9, conv + n-flank sum only (no barriers, no LDS writes) ========
    for (int l0 = 0; l0 < 10; l0 += 2) {
        CONV_PAIR(l0, a0,a1,a2,a3, e0,e1,e2,e3)
        sum_n[0] += a0 + e0; sum_n[1] += a1 + e1;
        sum_n[2] += a2 + e2; sum_n[3] += a3 + e3;
    }

    // ======== MID: l0 = 10..22, conv + c-flank sum + MLP both l (1 barrier/stage) ========
    // 4-slot ring on s_tile: stage l0 writes slots {l0&3,(l0+1)&3}; WAR distance = 2 stages
    // = 2 barriers. cm is auto-false for l < 10+plen (plen>=5 -> l<15).
    for (int l0 = YL0; l0 < 24; l0 += 2) {
        const int l1 = l0 + 1;
        CONV_PAIR(l0, a0,a1,a2,a3, e0,e1,e2,e3)
        {
            float cm0 = (l0 >= 10 + plen_lane && l0 < 20 + plen_lane) ? 1.0f : 0.0f;
            float cm1 = (l1 >= 10 + plen_lane && l1 < 20 + plen_lane) ? 1.0f : 0.0f;
            sum_c[0] += cm0 * a0 + cm1 * e0;
            sum_c[1] += cm0 * a1 + cm1 * e1;
            sum_c[2] += cm0 * a2 + cm1 * e2;
            sum_c[3] += cm0 * a3 + cm1 * e3;
        }
        ushort4 pk0 = { bf16bits(a0), bf16bits(a1), bf16bits(a2), bf16bits(a3) };
        ushort4 pk1 = { bf16bits(e0), bf16bits(e1), bf16bits(e2), bf16bits(e3) };
        *(ushort4*)&s_tile[l0 & 3][col * TILE_STRIDE + wave * 16 + 4 * quad] = pk0;
        *(ushort4*)&s_tile[l1 & 3][col * TILE_STRIDE + wave * 16 + 4 * quad] = pk1;
        __syncthreads();   // conv tiles written -> MLP may read; WAR fence for ring
        MLP_ONE(l0)
        MLP_ONE(l1)
    }

    // ======== PEEL: l0 = 24 (l=25 conv feeds sum_c only; MLP for l=24 only) ========
    {
        CONV_PAIR(24, a0,a1,a2,a3, e0,e1,e2,e3)
        {
            float cm0 = (24 >= 10 + plen_lane && 24 < 20 + plen_lane) ? 1.0f : 0.0f;
            float cm1 = (25 >= 10 + plen_lane && 25 < 20 + plen_lane) ? 1.0f : 0.0f;
            sum_c[0] += cm0 * a0 + cm1 * e0;
            sum_c[1] += cm0 * a1 + cm1 * e1;
            sum_c[2] += cm0 * a2 + cm1 * e2;
            sum_c[3] += cm0 * a3 + cm1 * e3;
        }
        ushort4 pk0 = { bf16bits(a0), bf16bits(a1), bf16bits(a2), bf16bits(a3) };
        *(ushort4*)&s_tile[24 & 3][col * TILE_STRIDE + wave * 16 + 4 * quad] = pk0;
        __syncthreads();
        MLP_ONE(24)
    }

    // ======== POST: l = 26..35, conv + c-flank sum only (l=35: cm auto-false) ========
    for (int l0 = 26; l0 < 36; l0 += 2) {
        const int l1 = l0 + 1;
        CONV_PAIR(l0, a0,a1,a2,a3, e0,e1,e2,e3)
        float cm0 = (l0 >= 10 + plen_lane && l0 < 20 + plen_lane) ? 1.0f : 0.0f;
        float cm1 = (l1 >= 10 + plen_lane && l1 < 20 + plen_lane) ? 1.0f : 0.0f;
        sum_c[0] += cm0 * a0 + cm1 * e0;
        sum_c[1] += cm0 * a1 + cm1 * e1;
        sum_c[2] += cm0 * a2 + cm1 * e2;
        sum_c[3] += cm0 * a3 + cm1 * e3;
    }
    __syncthreads();   // all s_seq reads + s_yp atomics done -> overlay safe

    // ---- flank-average partials: apply navg_w/cavg_w post-loop ----
    {
        float an = 0.f, ac = 0.f;
        #pragma unroll
        for (int r = 0; r < 4; r++) {
            int fidx = wave * 16 + 4 * quad + r;
            an += sum_n[r] * navg_w[fidx];
            ac += sum_c[r] * cavg_w[fidx];
        }
        an += __shfl_xor(an, 16); an += __shfl_xor(an, 32);   // sum over quads
        ac += __shfl_xor(ac, 16); ac += __shfl_xor(ac, 32);
        if (quad == 0) {                     // lane < 16: one per batch
            s_avg[wave * 2 * GB + 0 * GB + col] = an;
            s_avg[wave * 2 * GB + 1 * GB + col] = ac;
        }
    }
    // ---- y finalize in place: y = tanh(sum + b2), 480 values, conflict-free ----
    if (t < NYL * 2 * GB) {
        const int hd = (t >> 4) & 1;
        s_yp[t] = tanhf(s_yp[t] + (hd ? c_b2[0] : n_b2[0]));
    }
    __syncthreads();

    // ---- final combine: one thread per batch row ----
    if (t < GB) {
        const int m = t;
        const int plen = plen_arr[b0 + m];
        // s_yp[(l-10)*32 + head*16 + m]; lane m stays in its own bank
        float cleaved_n = s_yp[m];                              // l = 10, n-head
        float mn = 0.f;   // reference maxes (y+1)*mask over ALL l; unmasked give 0
        for (int l = 11; l < 10 + plen; l++)
            mn = fmaxf(mn, s_yp[(l - YL0) * 32 + m] + 1.f);
        float maxpool_n = -(mn - 1.f);
        float cleaved_c = s_yp[(plen - 1) * 32 + 16 + m];       // l = 10+plen-1, c-head
        float mc = 0.f;
        for (int l = 10; l < 10 + plen - 1; l++)
            mc = fmaxf(mc, s_yp[(l - YL0) * 32 + 16 + m] + 1.f);
        float maxpool_c = -(mc - 1.f);
        float sn = 0.f, sc = 0.f;
        #pragma unroll
        for (int w = 0; w < 8; w++) {
            sn += s_avg[w * 2 * GB + 0 * GB + m];
            sc += s_avg[w * 2 * GB + 1 * GB + m];
        }
        float avg_n = tanhf(sn * 0.1f + navg_b[0]);
        float avg_c = tanhf(sc * 0.1f + cavg_b[0]);
        float comb = cleaved_n * out_w[0] + maxpool_n * out_w[1] + avg_n * out_w[2]
                   + cleaved_c * out_w[3] + maxpool_c * out_w[4] + avg_c * out_w[5]
                   + out_b[0];
        out[b0 + m] = 1.f / (1.f + expf(-comb));
    }
}

extern "C" void kernel_launch(void* const* d_in, const int* in_sizes, int n_in,
                              void* d_out, int out_size, void* d_ws, size_t ws_size,
                              hipStream_t stream) {
    const int B = in_sizes[1];
    fused_kernel<<<B / GB, 512, 0, stream>>>(
        (const float*)d_in[0],  (const int*)d_in[1],
        (const float*)d_in[2],  (const float*)d_in[3],
        (const float*)d_in[4],  (const float*)d_in[5],
        (const float*)d_in[6],  (const float*)d_in[7],
        (const float*)d_in[8],  (const float*)d_in[9],
        (const float*)d_in[10], (const float*)d_in[11],
        (const float*)d_in[12], (const float*)d_in[13],
        (const float*)d_in[14], (const float*)d_in[15],
        (const float*)d_in[16], (const float*)d_in[17],
        (float*)d_out);
}

// Round 3
// 403.244 us; speedup vs baseline: 1.1385x; 1.0514x over previous
//
#include <hip/hip_runtime.h>
#include <hip/hip_bf16.h>
#include <math.h>

// Problem constants
#define Ln     35
#define CINn   21
#define CINP   24        // padded CIN (multiple of 8 -> aligned b128 im2col reads)
#define Fn     128
#define Kn     9
#define Hn     64
#define GB     16        // batch rows per block
#define SEQ_STRIDE 1064  // 44 rows*24 + 8 slack (shorts); l=35 window ends at 1064
#define TILE_STRIDE 136  // 128 + 8 pad (shorts)
#define YL0    10        // first l whose MLP output is ever consumed
#define NYL    15        // l in [10,24] consumed (plen<=15)

typedef __attribute__((ext_vector_type(8))) short short8;
typedef __attribute__((ext_vector_type(4))) float f32x4;

static __device__ __forceinline__ unsigned short bf16bits(float f) {
    __hip_bfloat16 h = __float2bfloat16(f);
    return *(unsigned short*)&h;
}

// conv GEMM for ONE l: declares A0..A3 = relu(conv+bias) for this lane's 4 f-rows.
// af[7] (28 VGPRs) is the ONLY transient fragment buffer; the trailing
// sched_barrier(0) pins the schedule so the next conv's ds_reads cannot be
// hoisted above this one's MFMAs (which would double fragment liveness and
// spill past the 128-reg/wave cap of __launch_bounds__(512,4)).
#define CONV_ONE(L, A0,A1,A2,A3)                                                           \
    float A0,A1,A2,A3;                                                                     \
    {                                                                                      \
        short8 af[7];                                                                      \
        _Pragma("unroll")                                                                  \
        for (int s = 0; s < 7; s++)                                                        \
            af[s] = *(const short8*)&s_seq[col*SEQ_STRIDE + (L)*CINP + 32*s + quad*8];     \
        f32x4 c0 = {0.f,0.f,0.f,0.f};                                                      \
        _Pragma("unroll")                                                                  \
        for (int s = 0; s < 7; s++)                                                        \
            c0 = __builtin_amdgcn_mfma_f32_16x16x32_bf16(wb[s], af[s], c0, 0, 0, 0);       \
        A0 = fmaxf(c0[0] + cbias[0], 0.f); A1 = fmaxf(c0[1] + cbias[1], 0.f);              \
        A2 = fmaxf(c0[2] + cbias[2], 0.f); A3 = fmaxf(c0[3] + cbias[3], 0.f);              \
    }                                                                                      \
    __builtin_amdgcn_sched_barrier(0);

// MLP for one l (slot = l&3): layer1 GEMM + relu*w2 + 16-col reduce + s_yp atomic add.
#define MLP_ONE(L)                                                                         \
    {                                                                                      \
        short8 am[4];                                                                      \
        _Pragma("unroll")                                                                  \
        for (int s = 0; s < 4; s++)                                                        \
            am[s] = *(const short8*)&s_tile[(L) & 3][col*TILE_STRIDE + 32*s + quad*8];     \
        f32x4 h = {0.f,0.f,0.f,0.f};                                                       \
        _Pragma("unroll")                                                                  \
        for (int s = 0; s < 4; s++)                                                        \
            h = __builtin_amdgcn_mfma_f32_16x16x32_bf16(am[s], w1b[s], h, 0, 0, 0);        \
        float p[4];                                                                        \
        _Pragma("unroll")                                                                  \
        for (int r = 0; r < 4; r++)                                                        \
            p[r] = fmaxf(h[r] + b1v, 0.f) * w2v;                                           \
        _Pragma("unroll")                                                                  \
        for (int r = 0; r < 4; r++) {                                                      \
            p[r] += __shfl_xor(p[r], 1);                                                   \
            p[r] += __shfl_xor(p[r], 2);                                                   \
            p[r] += __shfl_xor(p[r], 4);                                                   \
            p[r] += __shfl_xor(p[r], 8);                                                   \
        }                                                                                  \
        if (col == 0) {                                                                    \
            const int base = ((L) - YL0) * 32 + head * 16 + quad * 4;                      \
            atomicAdd(&s_yp[base + 0], p[0]);                                              \
            atomicAdd(&s_yp[base + 1], p[1]);                                              \
            atomicAdd(&s_yp[base + 2], p[2]);                                              \
            atomicAdd(&s_yp[base + 3], p[3]);                                              \
        }                                                                                  \
    }                                                                                      \
    __builtin_amdgcn_sched_barrier(0);

// ---------------- single fused kernel: 16 batch rows / block, 512 threads ----------------
// 8 waves/block; wave w owns conv f-tile [16w,16w+16) and MLP n-tile [16w,16w+16)
// (n<64 = n-head, n>=64 = c-head).
// Structure: four straight-line regions (no runtime branches in bodies):
//   pre  l=0..9   : conv + sum_n only, no barriers
//   mid  l0=10..22: conv + sum_c + tile write + barrier + MLP both l
//   peel l0=24    : conv(24,25) + sum_c + tile write(24) + barrier + MLP(24)
//   post l=26..35 : conv + sum_c only, no barriers (l=35 = computed pad, cm auto-false)
// y partials accumulate via LDS atomicAdd into s_yp[15][2][16] f32 (1.9 KB).
// Register budget (the round-2 lesson): persistent ~65 regs; conv transient capped
// at 28+8 by CONV_ONE's sched_barrier -> peak ~110 < 128 -> no scratch spill.
__global__ __launch_bounds__(512, 4) void fused_kernel(
    const float* __restrict__ seq,    const int*   __restrict__ plen_arr,
    const float* __restrict__ conv_w, const float* __restrict__ conv_b,
    const float* __restrict__ n_w1,   const float* __restrict__ n_b1,
    const float* __restrict__ n_w2,   const float* __restrict__ n_b2,
    const float* __restrict__ c_w1,   const float* __restrict__ c_b1,
    const float* __restrict__ c_w2,   const float* __restrict__ c_b2,
    const float* __restrict__ navg_w, const float* __restrict__ navg_b,
    const float* __restrict__ cavg_w, const float* __restrict__ cavg_b,
    const float* __restrict__ out_w,  const float* __restrict__ out_b,
    float* __restrict__ out)
{
    __shared__ __align__(16) unsigned short s_seq[GB * SEQ_STRIDE];      // 34048 B
    __shared__ __align__(16) unsigned short s_tile[4][GB * TILE_STRIDE]; // 17408 B
    __shared__ __align__(16) float s_yp[NYL * 2 * GB];                   // 1920 B: [l-10][head][m]
    // overlay on s_seq (dead after the main loops):
    float* s_avg = (float*)s_seq;            // [8 waves][2][GB] = 256 floats

    const int t    = threadIdx.x;
    const int wave = t >> 6;                 // 0..7
    const int lane = t & 63;
    const int quad = lane >> 4;
    const int col  = lane & 15;
    const int b0   = blockIdx.x * GB;

    // ---- zero-init padded seq (pad rows/channels + slack must be 0) + y accumulator ----
    {
        uint4* p = (uint4*)s_seq;            // 34048/16 = 2128 uint4
        for (int i = t; i < (GB * SEQ_STRIDE) / 8; i += 512)
            p[i] = make_uint4(0u, 0u, 0u, 0u);
        if (t < NYL * 2 * GB) s_yp[t] = 0.0f;
    }

    // ---- per-lane loop-invariant weight fragments (single tile per wave) ----
    // conv A-frag (operand-swapped): A[m=f=16*wave+col][k=kk], kk = k*24+c
    // MLP  B-frag: B[k=f][n=16*wave+col]
    short8 wb[7];
    short8 w1b[4];
    float  cbias[4], b1v, w2v;
    const int head = wave >> 2;              // 0 = n-head (waves 0-3), 1 = c (waves 4-7)
    {
        const int ng = wave * 16 + col;      // conv f (A m-index) AND mlp n-index
        #pragma unroll
        for (int s = 0; s < 7; s++) {
            short8 v;
            #pragma unroll
            for (int j = 0; j < 8; j++) {
                int kk = 32 * s + quad * 8 + j;
                int k = kk / CINP, c = kk % CINP;
                float f = (k < Kn && c < CINn) ? conv_w[(k * CINn + c) * Fn + ng] : 0.0f;
                v[j] = (short)bf16bits(f);
            }
            wb[s] = v;
        }
        const int nl = ng & 63;
        #pragma unroll
        for (int s = 0; s < 4; s++) {
            short8 v;
            #pragma unroll
            for (int j = 0; j < 8; j++) {
                int k = 32 * s + quad * 8 + j;
                float f = head ? c_w1[k * Hn + nl] : n_w1[k * Hn + nl];
                v[j] = (short)bf16bits(f);
            }
            w1b[s] = v;
        }
        #pragma unroll
        for (int r = 0; r < 4; r++)
            cbias[r] = conv_b[wave * 16 + 4 * quad + r];
        b1v = head ? c_b1[nl] : n_b1[nl];
        w2v = head ? c_w2[nl] : n_w2[nl];
    }
    const int plen_lane = plen_arr[b0 + col];   // this lane's batch (=col) plen

    __syncthreads();   // zero-init done before data fill

    // ---- stage seq -> bf16 LDS, rows shifted +4 (SAME pad), c<21 only ----
    // incremental (bi,l,c) walk: step 512 = 24 rows + 8 cols (avoids div/mod per iter)
    {
        int i  = t;
        int bi = i / (Ln * CINn);
        int r  = i - bi * (Ln * CINn);
        int l  = r / CINn;
        int c  = r - l * CINn;
        for (; i < GB * Ln * CINn; i += 512) {
            s_seq[bi * SEQ_STRIDE + (4 + l) * CINP + c] =
                bf16bits(seq[(size_t)b0 * (Ln * CINn) + i]);
            c += 8;  if (c >= CINn) { c -= CINn; ++l; }
            l += 24; if (l >= Ln)   { l -= Ln;  ++bi; }
        }
    }
    __syncthreads();

    float sum_n[4] = {0.f,0.f,0.f,0.f};
    float sum_c[4] = {0.f,0.f,0.f,0.f};

    // ======== PRE: l = 0..9, conv + n-flank sum only (no barriers, no LDS writes) ========
    for (int l0 = 0; l0 < 10; l0 += 2) {
        CONV_ONE(l0,     a0,a1,a2,a3)
        CONV_ONE(l0 + 1, e0,e1,e2,e3)
        sum_n[0] += a0 + e0; sum_n[1] += a1 + e1;
        sum_n[2] += a2 + e2; sum_n[3] += a3 + e3;
    }

    // ======== MID: l0 = 10..22, conv + c-flank sum + MLP both l (1 barrier/stage) ========
    // 4-slot ring on s_tile: stage l0 writes slots {l0&3,(l0+1)&3}; WAR distance = 2 stages
    // = 2 barriers. cm is auto-false for l < 10+plen (plen>=5 -> l<15).
    for (int l0 = YL0; l0 < 24; l0 += 2) {
        const int l1 = l0 + 1;
        CONV_ONE(l0, a0,a1,a2,a3)
        CONV_ONE(l1, e0,e1,e2,e3)
        {
            float cm0 = (l0 >= 10 + plen_lane && l0 < 20 + plen_lane) ? 1.0f : 0.0f;
            float cm1 = (l1 >= 10 + plen_lane && l1 < 20 + plen_lane) ? 1.0f : 0.0f;
            sum_c[0] += cm0 * a0 + cm1 * e0;
            sum_c[1] += cm0 * a1 + cm1 * e1;
            sum_c[2] += cm0 * a2 + cm1 * e2;
            sum_c[3] += cm0 * a3 + cm1 * e3;
        }
        ushort4 pk0 = { bf16bits(a0), bf16bits(a1), bf16bits(a2), bf16bits(a3) };
        ushort4 pk1 = { bf16bits(e0), bf16bits(e1), bf16bits(e2), bf16bits(e3) };
        *(ushort4*)&s_tile[l0 & 3][col * TILE_STRIDE + wave * 16 + 4 * quad] = pk0;
        *(ushort4*)&s_tile[l1 & 3][col * TILE_STRIDE + wave * 16 + 4 * quad] = pk1;
        __syncthreads();   // conv tiles written -> MLP may read; WAR fence for ring
        MLP_ONE(l0)
        MLP_ONE(l1)
    }

    // ======== PEEL: l0 = 24 (l=25 conv feeds sum_c only; MLP for l=24 only) ========
    {
        CONV_ONE(24, a0,a1,a2,a3)
        CONV_ONE(25, e0,e1,e2,e3)
        {
            float cm0 = (24 >= 10 + plen_lane && 24 < 20 + plen_lane) ? 1.0f : 0.0f;
            float cm1 = (25 >= 10 + plen_lane && 25 < 20 + plen_lane) ? 1.0f : 0.0f;
            sum_c[0] += cm0 * a0 + cm1 * e0;
            sum_c[1] += cm0 * a1 + cm1 * e1;
            sum_c[2] += cm0 * a2 + cm1 * e2;
            sum_c[3] += cm0 * a3 + cm1 * e3;
        }
        ushort4 pk0 = { bf16bits(a0), bf16bits(a1), bf16bits(a2), bf16bits(a3) };
        *(ushort4*)&s_tile[24 & 3][col * TILE_STRIDE + wave * 16 + 4 * quad] = pk0;
        __syncthreads();
        MLP_ONE(24)
    }

    // ======== POST: l = 26..35, conv + c-flank sum only (l=35: cm auto-false) ========
    for (int l0 = 26; l0 < 36; l0 += 2) {
        const int l1 = l0 + 1;
        CONV_ONE(l0, a0,a1,a2,a3)
        CONV_ONE(l1, e0,e1,e2,e3)
        float cm0 = (l0 >= 10 + plen_lane && l0 < 20 + plen_lane) ? 1.0f : 0.0f;
        float cm1 = (l1 >= 10 + plen_lane && l1 < 20 + plen_lane) ? 1.0f : 0.0f;
        sum_c[0] += cm0 * a0 + cm1 * e0;
        sum_c[1] += cm0 * a1 + cm1 * e1;
        sum_c[2] += cm0 * a2 + cm1 * e2;
        sum_c[3] += cm0 * a3 + cm1 * e3;
    }
    __syncthreads();   // all s_seq reads + s_yp atomics done -> overlay safe

    // ---- flank-average partials: apply navg_w/cavg_w post-loop ----
    {
        float an = 0.f, ac = 0.f;
        #pragma unroll
        for (int r = 0; r < 4; r++) {
            int fidx = wave * 16 + 4 * quad + r;
            an += sum_n[r] * navg_w[fidx];
            ac += sum_c[r] * cavg_w[fidx];
        }
        an += __shfl_xor(an, 16); an += __shfl_xor(an, 32);   // sum over quads
        ac += __shfl_xor(ac, 16); ac += __shfl_xor(ac, 32);
        if (quad == 0) {                     // lane < 16: one per batch
            s_avg[wave * 2 * GB + 0 * GB + col] = an;
            s_avg[wave * 2 * GB + 1 * GB + col] = ac;
        }
    }
    // ---- y finalize in place: y = tanh(sum + b2), 480 values, conflict-free ----
    if (t < NYL * 2 * GB) {
        const int hd = (t >> 4) & 1;
        s_yp[t] = tanhf(s_yp[t] + (hd ? c_b2[0] : n_b2[0]));
    }
    __syncthreads();

    // ---- final combine: one thread per batch row ----
    if (t < GB) {
        const int m = t;
        const int plen = plen_arr[b0 + m];
        // s_yp[(l-10)*32 + head*16 + m]; lane m stays in its own bank
        float cleaved_n = s_yp[m];                              // l = 10, n-head
        float mn = 0.f;   // reference maxes (y+1)*mask over ALL l; unmasked give 0
        for (int l = 11; l < 10 + plen; l++)
            mn = fmaxf(mn, s_yp[(l - YL0) * 32 + m] + 1.f);
        float maxpool_n = -(mn - 1.f);
        float cleaved_c = s_yp[(plen - 1) * 32 + 16 + m];       // l = 10+plen-1, c-head
        float mc = 0.f;
        for (int l = 10; l < 10 + plen - 1; l++)
            mc = fmaxf(mc, s_yp[(l - YL0) * 32 + 16 + m] + 1.f);
        float maxpool_c = -(mc - 1.f);
        float sn = 0.f, sc = 0.f;
        #pragma unroll
        for (int w = 0; w < 8; w++) {
            sn += s_avg[w * 2 * GB + 0 * GB + m];
            sc += s_avg[w * 2 * GB + 1 * GB + m];
        }
        float avg_n = tanhf(sn * 0.1f + navg_b[0]);
        float avg_c = tanhf(sc * 0.1f + cavg_b[0]);
        float comb = cleaved_n * out_w[0] + maxpool_n * out_w[1] + avg_n * out_w[2]
                   + cleaved_c * out_w[3] + maxpool_c * out_w[4] + avg_c * out_w[5]
                   + out_b[0];
        out[b0 + m] = 1.f / (1.f + expf(-comb));
    }
}

extern "C" void kernel_launch(void* const* d_in, const int* in_sizes, int n_in,
                              void* d_out, int out_size, void* d_ws, size_t ws_size,
                              hipStream_t stream) {
    const int B = in_sizes[1];
    fused_kernel<<<B / GB, 512, 0, stream>>>(
        (const float*)d_in[0],  (const int*)d_in[1],
        (const float*)d_in[2],  (const float*)d_in[3],
        (const float*)d_in[4],  (const float*)d_in[5],
        (const float*)d_in[6],  (const float*)d_in[7],
        (const float*)d_in[8],  (const float*)d_in[9],
        (const float*)d_in[10], (const float*)d_in[11],
        (const float*)d_in[12], (const float*)d_in[13],
        (const float*)d_in[14], (const float*)d_in[15],
        (const float*)d_in[16], (const float*)d_in[17],
        (float*)d_out);
}